// Round 1
// baseline (116.307 us; speedup 1.0000x reference)
//
#include <hip/hip_runtime.h>
#include <math.h>

#define E_N 40000
#define D_N 200
#define L_N 100
#define B_N 32
#define K_N 300   // D + L

// ws layout (floats):
//  p_T   [300][32] @ 0       p[b,k] = sum_d q[b,d]*W[d,k]
//  sh_T  [100][32] @ 9600    r[l]*(num_lit[e1[b],l] - c[l])
//  w_T   [100][32] @ 12800   nf_w[rel[b],l]
//  s0    [32]      @ 16000   q[b,:]. b_lit
//  nr    [100]     @ 16032   -r[l],  r[l] = sqrt(log2(e)/var[l])

__device__ inline float fast_exp2(float x) {
#if __has_builtin(__builtin_amdgcn_exp2f)
    return __builtin_amdgcn_exp2f(x);
#else
    return exp2f(x);
#endif
}
__device__ inline float fast_rcp(float x) {
#if __has_builtin(__builtin_amdgcn_rcpf)
    return __builtin_amdgcn_rcpf(x);
#else
    return 1.0f / x;
#endif
}

__global__ __launch_bounds__(320) void prep_kernel(
    const int* __restrict__ e1, const int* __restrict__ rel,
    const float* __restrict__ emb_e, const float* __restrict__ emb_rel,
    const float* __restrict__ num_lit, const float* __restrict__ num_lit_norm,
    const float* __restrict__ W, const float* __restrict__ b_lit,
    const float* __restrict__ c, const float* __restrict__ var,
    const float* __restrict__ nf_w, float* __restrict__ ws)
{
    const int b = blockIdx.x;
    const int t = threadIdx.x;
    __shared__ float q[D_N];
    const int e1b = e1[b];
    const int rb  = rel[b];

    if (t < D_N) {
        const float* wr = W + t * K_N;            // row d=t of W (D, D+L)
        const float* er = emb_e + (long)e1b * D_N;
        const float* nl = num_lit_norm + (long)e1b * L_N;
        float s = b_lit[t];
        for (int k = 0; k < D_N; ++k) s += er[k] * wr[k];
        for (int k = 0; k < L_N; ++k) s += nl[k] * wr[D_N + k];
        q[t] = s * emb_rel[rb * D_N + t];         // q[b,d] = e1_emb * rel_emb
    }
    __syncthreads();

    if (t < K_N) {                                 // p_T[k][b]
        float s = 0.f;
        for (int d = 0; d < D_N; ++d) s += q[d] * W[d * K_N + t];
        ws[t * 32 + b] = s;
    }
    if (t < L_N) {                                 // sh_T, w_T (+ nr once)
        float r = sqrtf(1.4426950408889634f / var[t]);
        ws[9600  + t * 32 + b] = r * (num_lit[(long)e1b * L_N + t] - c[t]);
        ws[12800 + t * 32 + b] = nf_w[rb * L_N + t];
        if (b == 0) ws[16032 + t] = -r;
    }
    if (t == 300) {                                // s0[b]
        float s = 0.f;
        for (int d = 0; d < D_N; ++d) s += q[d] * b_lit[d];
        ws[16000 + b] = s;
    }
}

#define FMA8(PBASE, SCAL)                                            \
    do {                                                             \
        float4 p0_ = *(const float4*)((PBASE));                      \
        float4 p1_ = *(const float4*)((PBASE) + 4);                  \
        acc[0] = fmaf(p0_.x, (SCAL), acc[0]);                        \
        acc[1] = fmaf(p0_.y, (SCAL), acc[1]);                        \
        acc[2] = fmaf(p0_.z, (SCAL), acc[2]);                        \
        acc[3] = fmaf(p0_.w, (SCAL), acc[3]);                        \
        acc[4] = fmaf(p1_.x, (SCAL), acc[4]);                        \
        acc[5] = fmaf(p1_.y, (SCAL), acc[5]);                        \
        acc[6] = fmaf(p1_.z, (SCAL), acc[6]);                        \
        acc[7] = fmaf(p1_.w, (SCAL), acc[7]);                        \
    } while (0)

__global__ __launch_bounds__(256) void score_kernel(
    const float* __restrict__ emb_e, const float* __restrict__ num_lit,
    const float* __restrict__ num_lit_norm, const float* __restrict__ ws,
    float* __restrict__ out)
{
    const int t  = threadIdx.x;
    const int bq = t & 3;
    const int b0 = bq * 8;
    const int e  = blockIdx.x * 64 + (t >> 2);

    const float* p  = ws;
    const float* sh = ws + 9600;
    const float* w  = ws + 12800;
    const float* s0 = ws + 16000;
    const float* nr = ws + 16032;

    float acc[8];
#pragma unroll
    for (int j = 0; j < 8; ++j) acc[j] = s0[b0 + j];

    // ---- phase 1: score_l, emb_e part (k = 0..199) ----
    const float* er = emb_e + (long)e * D_N;
    for (int k = 0; k < D_N; k += 4) {
        float4 ev = *(const float4*)(er + k);
        float evs[4] = {ev.x, ev.y, ev.z, ev.w};
#pragma unroll
        for (int kk = 0; kk < 4; ++kk) {
            FMA8(p + (k + kk) * 32 + b0, evs[kk]);
        }
    }

    // ---- phase 2: score_l, num_lit_norm part (k = 200..299) ----
    const float* nn = num_lit_norm + (long)e * L_N;
    const float* p2 = p + D_N * 32;
    for (int l = 0; l < L_N; l += 4) {
        float4 ev = *(const float4*)(nn + l);
        float evs[4] = {ev.x, ev.y, ev.z, ev.w};
#pragma unroll
        for (int kk = 0; kk < 4; ++kk) {
            FMA8(p2 + (l + kk) * 32 + b0, evs[kk]);
        }
    }

    // ---- phase 3: score_n, RBF part ----
    const float* ml = num_lit + (long)e * L_N;
    for (int l = 0; l < L_N; l += 4) {
        float4 mv  = *(const float4*)(ml + l);
        float4 nrv = *(const float4*)(nr + l);
        float mvs[4] = {mv.x, mv.y, mv.z, mv.w};
        float nrs[4] = {nrv.x, nrv.y, nrv.z, nrv.w};
#pragma unroll
        for (int ll = 0; ll < 4; ++ll) {
            const float rm = nrs[ll] * mvs[ll];
            const float* shp = sh + (l + ll) * 32 + b0;
            const float* wp  = w  + (l + ll) * 32 + b0;
            float4 s0v = *(const float4*)(shp);
            float4 s1v = *(const float4*)(shp + 4);
            float4 w0v = *(const float4*)(wp);
            float4 w1v = *(const float4*)(wp + 4);
            float u;
            u = rm + s0v.x; acc[0] = fmaf(fast_exp2(-(u * u)), w0v.x, acc[0]);
            u = rm + s0v.y; acc[1] = fmaf(fast_exp2(-(u * u)), w0v.y, acc[1]);
            u = rm + s0v.z; acc[2] = fmaf(fast_exp2(-(u * u)), w0v.z, acc[2]);
            u = rm + s0v.w; acc[3] = fmaf(fast_exp2(-(u * u)), w0v.w, acc[3]);
            u = rm + s1v.x; acc[4] = fmaf(fast_exp2(-(u * u)), w1v.x, acc[4]);
            u = rm + s1v.y; acc[5] = fmaf(fast_exp2(-(u * u)), w1v.y, acc[5]);
            u = rm + s1v.z; acc[6] = fmaf(fast_exp2(-(u * u)), w1v.z, acc[6]);
            u = rm + s1v.w; acc[7] = fmaf(fast_exp2(-(u * u)), w1v.w, acc[7]);
        }
    }

    // ---- sigmoid + store ----
#pragma unroll
    for (int j = 0; j < 8; ++j) {
        float z = fast_exp2(acc[j] * -1.4426950408889634f);
        out[(long)(b0 + j) * E_N + e] = fast_rcp(1.0f + z);
    }
}

extern "C" void kernel_launch(void* const* d_in, const int* in_sizes, int n_in,
                              void* d_out, int out_size, void* d_ws, size_t ws_size,
                              hipStream_t stream) {
    const int*   e1       = (const int*)d_in[0];
    const int*   rel      = (const int*)d_in[1];
    const float* emb_e    = (const float*)d_in[2];
    const float* emb_rel  = (const float*)d_in[3];
    const float* num_lit  = (const float*)d_in[4];
    const float* num_lit_norm = (const float*)d_in[5];
    const float* W_lit    = (const float*)d_in[6];
    const float* b_lit    = (const float*)d_in[7];
    const float* c        = (const float*)d_in[8];
    const float* var      = (const float*)d_in[9];
    const float* nf_w     = (const float*)d_in[10];
    float* out = (float*)d_out;
    float* ws  = (float*)d_ws;

    hipLaunchKernelGGL(prep_kernel, dim3(B_N), dim3(320), 0, stream,
                       e1, rel, emb_e, emb_rel, num_lit, num_lit_norm,
                       W_lit, b_lit, c, var, nf_w, ws);
    hipLaunchKernelGGL(score_kernel, dim3(E_N / 64), dim3(256), 0, stream,
                       emb_e, num_lit, num_lit_norm, ws, out);
}

// Round 2
// 52.846 us; speedup vs baseline: 2.2008x; 2.2008x over previous
//
#include <hip/hip_runtime.h>
#include <math.h>

#define E_N 40000
#define D_N 200
#define L_N 100
#define K_N 300
#define B_N 32

typedef float  f32x4 __attribute__((ext_vector_type(4)));
typedef short  s16x8 __attribute__((ext_vector_type(8)));

// ws layout (f32 units):
//  sh  [100][32] @ 0      r_l*(num_lit[e1_b,l]-c_l)
//  w   [100][32] @ 3200   nf_w[rel_b,l]
//  nr  [100]     @ 6400   -r_l,  r_l = sqrt(log2e/var_l)
//  s0  [32]      @ 6500   q[b,:].b_lit
//  pA  u16[2][10][64][8] @ 6532   p in MFMA A-frag layout, bf16, zero-pad k>=300
#define WS_SH 0
#define WS_W  3200
#define WS_NR 6400
#define WS_S0 6500
#define WS_PA 6532          // f32 offset; as u16 offset = 13064
#define WS_TOT 11652        // f32 (46608 bytes = 2913 float4)

__device__ inline float fast_exp2(float x) {
#if __has_builtin(__builtin_amdgcn_exp2f)
    return __builtin_amdgcn_exp2f(x);
#else
    return exp2f(x);
#endif
}
__device__ inline float fast_rcp(float x) {
#if __has_builtin(__builtin_amdgcn_rcpf)
    return __builtin_amdgcn_rcpf(x);
#else
    return 1.0f / x;
#endif
}
__device__ inline ushort f2bf(float f) {        // round-to-nearest-even f32->bf16
    uint u = __builtin_bit_cast(uint, f);
    u += 0x7fffu + ((u >> 16) & 1u);
    return (ushort)(u >> 16);
}

__global__ __launch_bounds__(320) void prep_kernel(
    const int* __restrict__ e1, const int* __restrict__ rel,
    const float* __restrict__ emb_e, const float* __restrict__ emb_rel,
    const float* __restrict__ num_lit, const float* __restrict__ num_lit_norm,
    const float* __restrict__ W, const float* __restrict__ b_lit,
    const float* __restrict__ c, const float* __restrict__ var,
    const float* __restrict__ nf_w, float* __restrict__ ws)
{
    const int b = blockIdx.x;
    const int t = threadIdx.x;
    __shared__ float q[D_N];
    const int e1b = e1[b];
    const int rb  = rel[b];

    if (t < D_N) {
        const float* wr = W + t * K_N;
        const float* er = emb_e + (long)e1b * D_N;
        const float* nl = num_lit_norm + (long)e1b * L_N;
        float s0_ = b_lit[t], s1_ = 0.f, s2_ = 0.f, s3_ = 0.f;
        for (int k = 0; k < D_N; k += 4) {          // 4 partials: break dep chain
            s0_ += er[k+0] * wr[k+0]; s1_ += er[k+1] * wr[k+1];
            s2_ += er[k+2] * wr[k+2]; s3_ += er[k+3] * wr[k+3];
        }
        for (int k = 0; k < L_N; k += 4) {
            s0_ += nl[k+0] * wr[D_N+k+0]; s1_ += nl[k+1] * wr[D_N+k+1];
            s2_ += nl[k+2] * wr[D_N+k+2]; s3_ += nl[k+3] * wr[D_N+k+3];
        }
        q[t] = ((s0_ + s1_) + (s2_ + s3_)) * emb_rel[rb * D_N + t];
    }
    __syncthreads();

    // p[b,k] = sum_d q[d]*W[d,k]  -> bf16, stored directly in A-frag layout
    {
        float pk = 0.f;
        if (t < K_N) {
            float a0 = 0.f, a1 = 0.f, a2 = 0.f, a3 = 0.f;
            for (int d = 0; d < D_N; d += 4) {
                a0 += q[d+0] * W[(d+0) * K_N + t];
                a1 += q[d+1] * W[(d+1) * K_N + t];
                a2 += q[d+2] * W[(d+2) * K_N + t];
                a3 += q[d+3] * W[(d+3) * K_N + t];
            }
            pk = (a0 + a1) + (a2 + a3);
        }
        // t in [300,320) stays 0 -> zero padding
        const int s  = t >> 5;
        const int g  = (t >> 3) & 3;
        const int j  = t & 7;
        const int mt = b >> 4;
        const int ln = (g << 4) | (b & 15);
        ushort* pa = (ushort*)(ws + WS_PA);
        pa[((mt * 10 + s) * 64 + ln) * 8 + j] = f2bf(pk);
    }

    if (t < L_N) {
        const float r = sqrtf(1.4426950408889634f / var[t]);
        ws[WS_SH + t * 32 + b] = r * (num_lit[(long)e1b * L_N + t] - c[t]);
        ws[WS_W  + t * 32 + b] = nf_w[rb * L_N + t];
        if (b == 0) ws[WS_NR + t] = -r;
    }
    if (t == 300) {
        float s = 0.f;
        for (int d = 0; d < D_N; ++d) s += q[d] * b_lit[d];
        ws[WS_S0 + b] = s;
    }
}

__global__ __launch_bounds__(256) void score_kernel(
    const float* __restrict__ emb_e, const float* __restrict__ num_lit,
    const float* __restrict__ num_lit_norm, const float* __restrict__ ws,
    float* __restrict__ out)
{
    __shared__ float smem[WS_TOT];
    {   // cooperative stage of all tables (46608 B = 2913 float4, exact)
        const f32x4* s4 = (const f32x4*)ws;
        f32x4* d4 = (f32x4*)smem;
        for (int i = threadIdx.x; i < 2913; i += 256) d4[i] = s4[i];
    }
    __syncthreads();

    const int lane = threadIdx.x & 63;
    const int wv   = threadIdx.x >> 6;
    const int tile = blockIdx.x * 4 + wv;      // [0, 5000)
    const int mt   = tile & 1;                 // b-half
    const int eg   = tile >> 1;                // e-group
    const int e0   = eg * 16;
    const int er   = lane & 15;
    const int g    = lane >> 4;
    const int e    = e0 + er;
    const int b0   = mt * 16 + 4 * g;          // this lane's 4 b's: b0..b0+3

    const float*  shL = smem + WS_SH;
    const float*  wL  = smem + WS_W;
    const float*  nrL = smem + WS_NR;
    const float*  s0L = smem + WS_S0;
    const ushort* pA  = (const ushort*)(smem + WS_PA);

    f32x4 acc = *(const f32x4*)(s0L + b0);

    const float* embr = emb_e        + (long)e * D_N;
    const float* litn = num_lit_norm + (long)e * L_N;

    // ---- score_l via MFMA: D[b,e] = sum_k p[b,k]*cat_e[k] ----
#pragma unroll
    for (int s = 0; s < 9; ++s) {
        s16x8 a = *(const s16x8*)(pA + ((mt * 10 + s) * 64 + lane) * 8);
        const int k0 = 32 * s + 8 * g;
        const float* bp = (k0 < 200) ? (embr + k0) : (litn + (k0 - 200));
        f32x4 lo = *(const f32x4*)bp;
        f32x4 hi = *(const f32x4*)(bp + 4);
        s16x8 bb;
        bb[0] = (short)f2bf(lo[0]); bb[1] = (short)f2bf(lo[1]);
        bb[2] = (short)f2bf(lo[2]); bb[3] = (short)f2bf(lo[3]);
        bb[4] = (short)f2bf(hi[0]); bb[5] = (short)f2bf(hi[1]);
        bb[6] = (short)f2bf(hi[2]); bb[7] = (short)f2bf(hi[3]);
        acc = __builtin_amdgcn_mfma_f32_16x16x32_bf16(a, bb, acc, 0, 0, 0);
    }
    {   // step 9: k = 288..319 (real lit 88..99, zero-pad beyond)
        s16x8 a = *(const s16x8*)(pA + ((mt * 10 + 9) * 64 + lane) * 8);
        f32x4 z = {0.f, 0.f, 0.f, 0.f};
        f32x4 lo = z, hi = z;
        if (g == 0)      { lo = *(const f32x4*)(litn + 88); hi = *(const f32x4*)(litn + 92); }
        else if (g == 1) { lo = *(const f32x4*)(litn + 96); }
        s16x8 bb;
        bb[0] = (short)f2bf(lo[0]); bb[1] = (short)f2bf(lo[1]);
        bb[2] = (short)f2bf(lo[2]); bb[3] = (short)f2bf(lo[3]);
        bb[4] = (short)f2bf(hi[0]); bb[5] = (short)f2bf(hi[1]);
        bb[6] = (short)f2bf(hi[2]); bb[7] = (short)f2bf(hi[3]);
        acc = __builtin_amdgcn_mfma_f32_16x16x32_bf16(a, bb, acc, 0, 0, 0);
    }

    // ---- score_n: RBF over 100 literals (3 VALU + 1 exp2 per element) ----
    const float* mrow = num_lit + (long)e * L_N;
    for (int lc = 0; lc < 25; ++lc) {
        f32x4 mv = *(const f32x4*)(mrow + lc * 4);
        f32x4 nv = *(const f32x4*)(nrL + lc * 4);
#pragma unroll
        for (int ll = 0; ll < 4; ++ll) {
            const int l = lc * 4 + ll;
            const float rm = nv[ll] * mv[ll];
            f32x4 s4 = *(const f32x4*)(shL + l * 32 + b0);
            f32x4 w4 = *(const f32x4*)(wL  + l * 32 + b0);
#pragma unroll
            for (int j = 0; j < 4; ++j) {
                const float u = rm + s4[j];
                acc[j] = fmaf(fast_exp2(-(u * u)), w4[j], acc[j]);
            }
        }
    }

    // ---- sigmoid + store (lanes 0-15 share b -> 64B coalesced chunks) ----
#pragma unroll
    for (int j = 0; j < 4; ++j) {
        const float z = fast_exp2(acc[j] * -1.4426950408889634f);
        out[(long)(b0 + j) * E_N + e] = fast_rcp(1.0f + z);
    }
}

extern "C" void kernel_launch(void* const* d_in, const int* in_sizes, int n_in,
                              void* d_out, int out_size, void* d_ws, size_t ws_size,
                              hipStream_t stream) {
    const int*   e1       = (const int*)d_in[0];
    const int*   rel      = (const int*)d_in[1];
    const float* emb_e    = (const float*)d_in[2];
    const float* emb_rel  = (const float*)d_in[3];
    const float* num_lit  = (const float*)d_in[4];
    const float* num_lit_norm = (const float*)d_in[5];
    const float* W_lit    = (const float*)d_in[6];
    const float* b_lit    = (const float*)d_in[7];
    const float* c        = (const float*)d_in[8];
    const float* var      = (const float*)d_in[9];
    const float* nf_w     = (const float*)d_in[10];
    float* out = (float*)d_out;
    float* ws  = (float*)d_ws;

    hipLaunchKernelGGL(prep_kernel, dim3(B_N), dim3(320), 0, stream,
                       e1, rel, emb_e, emb_rel, num_lit, num_lit_norm,
                       W_lit, b_lit, c, var, nf_w, ws);
    hipLaunchKernelGGL(score_kernel, dim3(1250), dim3(256), 0, stream,
                       emb_e, num_lit, num_lit_norm, ws, out);
}

// Round 4
// 47.079 us; speedup vs baseline: 2.4705x; 1.1225x over previous
//
#include <hip/hip_runtime.h>
#include <math.h>

#define E_N 40000
#define D_N 200
#define L_N 100
#define K_N 300
#define B_N 32

typedef float  f32x4 __attribute__((ext_vector_type(4)));
typedef short  s16x8 __attribute__((ext_vector_type(8)));

// ws layout (f32 units):
//  sh  [100][32] @ 0      r_l*(num_lit[e1_b,l]-c_l)
//  w   [100][32] @ 3200   nf_w[rel_b,l]
//  nr  [100]     @ 6400   -r_l,  r_l = sqrt(log2e/var_l)
//  s0  [32]      @ 6500   q[b,:].b_lit   (pad to 6532)
//  pA  u16[2][10][64][8] @ 6532   p in MFMA A-frag layout, bf16, zero-pad k>=300
#define WS_SH 0
#define WS_W  3200
#define WS_NR 6400
#define WS_S0 6500
#define WS_STAGE 6532       // floats staged to LDS (= 26128 B = 1633 float4)
#define WS_PA 6532

__device__ inline float fast_exp2(float x) {
#if __has_builtin(__builtin_amdgcn_exp2f)
    return __builtin_amdgcn_exp2f(x);
#else
    return exp2f(x);
#endif
}
__device__ inline float fast_rcp(float x) {
#if __has_builtin(__builtin_amdgcn_rcpf)
    return __builtin_amdgcn_rcpf(x);
#else
    return 1.0f / x;
#endif
}
__device__ inline ushort f2bf(float f) {        // RNE f32->bf16 (round-2-proven)
    uint u = __builtin_bit_cast(uint, f);
    u += 0x7fffu + ((u >> 16) & 1u);
    return (ushort)(u >> 16);
}
__device__ inline s16x8 pack_bf8(f32x4 lo, f32x4 hi) {   // round-2-proven path
    s16x8 bb;
    bb[0] = (short)f2bf(lo[0]); bb[1] = (short)f2bf(lo[1]);
    bb[2] = (short)f2bf(lo[2]); bb[3] = (short)f2bf(lo[3]);
    bb[4] = (short)f2bf(hi[0]); bb[5] = (short)f2bf(hi[1]);
    bb[6] = (short)f2bf(hi[2]); bb[7] = (short)f2bf(hi[3]);
    return bb;
}

__global__ __launch_bounds__(320) void prep_kernel(
    const int* __restrict__ e1, const int* __restrict__ rel,
    const float* __restrict__ emb_e, const float* __restrict__ emb_rel,
    const float* __restrict__ num_lit, const float* __restrict__ num_lit_norm,
    const float* __restrict__ W, const float* __restrict__ b_lit,
    const float* __restrict__ c, const float* __restrict__ var,
    const float* __restrict__ nf_w, float* __restrict__ ws)
{
    const int b = blockIdx.x;
    const int t = threadIdx.x;
    __shared__ float q[D_N];
    const int e1b = e1[b];
    const int rb  = rel[b];

    if (t < D_N) {
        const float* wr = W + t * K_N;
        const float* er = emb_e + (long)e1b * D_N;
        const float* nl = num_lit_norm + (long)e1b * L_N;
        float s0_ = b_lit[t], s1_ = 0.f, s2_ = 0.f, s3_ = 0.f;
        for (int k = 0; k < D_N; k += 4) {
            s0_ += er[k+0] * wr[k+0]; s1_ += er[k+1] * wr[k+1];
            s2_ += er[k+2] * wr[k+2]; s3_ += er[k+3] * wr[k+3];
        }
        for (int k = 0; k < L_N; k += 4) {
            s0_ += nl[k+0] * wr[D_N+k+0]; s1_ += nl[k+1] * wr[D_N+k+1];
            s2_ += nl[k+2] * wr[D_N+k+2]; s3_ += nl[k+3] * wr[D_N+k+3];
        }
        q[t] = ((s0_ + s1_) + (s2_ + s3_)) * emb_rel[rb * D_N + t];
    }
    __syncthreads();

    {   // p[b,k] = sum_d q[d]*W[d,k]  -> bf16, A-frag layout
        float pk = 0.f;
        if (t < K_N) {
            float a0 = 0.f, a1 = 0.f, a2 = 0.f, a3 = 0.f;
            for (int d = 0; d < D_N; d += 4) {
                a0 += q[d+0] * W[(d+0) * K_N + t];
                a1 += q[d+1] * W[(d+1) * K_N + t];
                a2 += q[d+2] * W[(d+2) * K_N + t];
                a3 += q[d+3] * W[(d+3) * K_N + t];
            }
            pk = (a0 + a1) + (a2 + a3);
        }
        const int s  = t >> 5;
        const int g  = (t >> 3) & 3;
        const int j  = t & 7;
        const int mt = b >> 4;
        const int ln = (g << 4) | (b & 15);
        ushort* pa = (ushort*)(ws + WS_PA);
        pa[((mt * 10 + s) * 64 + ln) * 8 + j] = f2bf(pk);
    }

    if (t < L_N) {
        const float r = sqrtf(1.4426950408889634f / var[t]);
        ws[WS_SH + t * 32 + b] = r * (num_lit[(long)e1b * L_N + t] - c[t]);
        ws[WS_W  + t * 32 + b] = nf_w[rb * L_N + t];
        if (b == 0) ws[WS_NR + t] = -r;
    }
    if (t == 300) {
        float s = 0.f;
        for (int d = 0; d < D_N; ++d) s += q[d] * b_lit[d];
        ws[WS_S0 + b] = s;
    }
}

__global__ __launch_bounds__(256, 4) void score_kernel(
    const float* __restrict__ emb_e, const float* __restrict__ num_lit,
    const float* __restrict__ num_lit_norm, const float* __restrict__ ws,
    float* __restrict__ out)
{
    __shared__ float smem[WS_STAGE];

    const int lane = threadIdx.x & 63;
    const int wv   = threadIdx.x >> 6;
    const int tile = blockIdx.x * 4 + wv;      // [0, 5000)
    const int mt   = tile & 1;                 // b-half
    const int eg   = tile >> 1;                // e-group
    const int er   = lane & 15;
    const int g    = lane >> 4;
    const int e    = eg * 16 + er;
    const int b0   = mt * 16 + 4 * g;

    // ---- A fragments: global -> registers (coalesced 16B/lane, dead after MFMA)
    s16x8 afr[10];
    {
        const s16x8* pAg = (const s16x8*)(ws + WS_PA);
#pragma unroll
        for (int s = 0; s < 10; ++s) afr[s] = pAg[(mt * 10 + s) * 64 + lane];
    }

    // ---- cooperative stage of RBF tables (26128 B = 1633 float4, exact)
    {
        const f32x4* s4 = (const f32x4*)ws;
        f32x4* d4 = (f32x4*)smem;
        for (int i = threadIdx.x; i < 1633; i += 256) d4[i] = s4[i];
    }
    __syncthreads();

    const float* shL = smem + WS_SH;
    const float* wL  = smem + WS_W;
    const float* nrL = smem + WS_NR;
    const float* s0L = smem + WS_S0;

    f32x4 acc = *(const f32x4*)(s0L + b0);

    const float* embr = emb_e        + (long)e * D_N;
    const float* litn = num_lit_norm + (long)e * L_N;

    // ---- score_l via MFMA: D[b,e] = sum_k p[b,k]*cat_e[k] ----
#pragma unroll
    for (int s = 0; s < 9; ++s) {
        const int k0 = 32 * s + 8 * g;
        const float* bp = (k0 < 200) ? (embr + k0) : (litn + (k0 - 200));
        f32x4 lo = *(const f32x4*)bp;
        f32x4 hi = *(const f32x4*)(bp + 4);
        acc = __builtin_amdgcn_mfma_f32_16x16x32_bf16(afr[s], pack_bf8(lo, hi), acc, 0, 0, 0);
    }
    {   // step 9: k = 288..319 (real lit 88..99; A is zero-padded for k>=300)
        f32x4 z = {0.f, 0.f, 0.f, 0.f};
        f32x4 lo = z, hi = z;
        if (g == 0)      { lo = *(const f32x4*)(litn + 88); hi = *(const f32x4*)(litn + 92); }
        else if (g == 1) { lo = *(const f32x4*)(litn + 96); }
        acc = __builtin_amdgcn_mfma_f32_16x16x32_bf16(afr[9], pack_bf8(lo, hi), acc, 0, 0, 0);
    }

    // ---- score_n: RBF over 100 literals ----
    const float* mrow = num_lit + (long)e * L_N;
    for (int lc = 0; lc < 25; ++lc) {
        f32x4 mv = *(const f32x4*)(mrow + lc * 4);
        f32x4 nv = *(const f32x4*)(nrL + lc * 4);
#pragma unroll
        for (int ll = 0; ll < 4; ++ll) {
            const int l = lc * 4 + ll;
            const float rm = nv[ll] * mv[ll];
            f32x4 s4 = *(const f32x4*)(shL + l * 32 + b0);
            f32x4 w4 = *(const f32x4*)(wL  + l * 32 + b0);
#pragma unroll
            for (int j = 0; j < 4; ++j) {
                const float u = rm + s4[j];
                acc[j] = fmaf(fast_exp2(-(u * u)), w4[j], acc[j]);
            }
        }
    }

    // ---- sigmoid + store ----
#pragma unroll
    for (int j = 0; j < 4; ++j) {
        const float z = fast_exp2(acc[j] * -1.4426950408889634f);
        out[(long)(b0 + j) * E_N + e] = fast_rcp(1.0f + z);
    }
}

extern "C" void kernel_launch(void* const* d_in, const int* in_sizes, int n_in,
                              void* d_out, int out_size, void* d_ws, size_t ws_size,
                              hipStream_t stream) {
    const int*   e1       = (const int*)d_in[0];
    const int*   rel      = (const int*)d_in[1];
    const float* emb_e    = (const float*)d_in[2];
    const float* emb_rel  = (const float*)d_in[3];
    const float* num_lit  = (const float*)d_in[4];
    const float* num_lit_norm = (const float*)d_in[5];
    const float* W_lit    = (const float*)d_in[6];
    const float* b_lit    = (const float*)d_in[7];
    const float* c        = (const float*)d_in[8];
    const float* var      = (const float*)d_in[9];
    const float* nf_w     = (const float*)d_in[10];
    float* out = (float*)d_out;
    float* ws  = (float*)d_ws;

    hipLaunchKernelGGL(prep_kernel, dim3(B_N), dim3(320), 0, stream,
                       e1, rel, emb_e, emb_rel, num_lit, num_lit_norm,
                       W_lit, b_lit, c, var, nf_w, ws);
    hipLaunchKernelGGL(score_kernel, dim3(1250), dim3(256), 0, stream,
                       emb_e, num_lit, num_lit_norm, ws, out);
}